// Round 7
// baseline (332.352 us; speedup 1.0000x reference)
//
#include <hip/hip_runtime.h>
#include <hip/hip_bf16.h>
#include <cstdint>

// Problem constants: B=4, T=2048, D_MODEL=1024, H=16, Dh=64
#define TT      2048
#define NBATCH  4
#define BTROWS  8192        // B*T
#define CDIM    1024
#define NQKV    3072
// Q pre-scale: 1/sqrt(64) * log2(e)  (so attention uses exp2)
#define QSCALE  0.18033688011112042f

using bf16x8 = __attribute__((ext_vector_type(8))) short;
using f32x4  = __attribute__((ext_vector_type(4))) float;
using f32x16 = __attribute__((ext_vector_type(16))) float;

#define GLOAD_LDS16(g, l)                                                     \
  __builtin_amdgcn_global_load_lds(                                           \
      (const __attribute__((address_space(1))) unsigned int*)(g),             \
      (__attribute__((address_space(3))) unsigned int*)(l), 16, 0, 0)

__device__ inline short f2bf(float f) {
  unsigned u = __builtin_bit_cast(unsigned, f);
  u += 0x7FFF + ((u >> 16) & 1);   // RNE
  return (short)(u >> 16);
}

// ---------------- fp32 -> bf16 conversion ----------------
__global__ __launch_bounds__(256) void conv_bf16(const float* __restrict__ in,
                                                 short* __restrict__ out, int n) {
  int i = (blockIdx.x * 256 + threadIdx.x) * 4;
  if (i + 3 < n) {
    float4 v = *(const float4*)(in + i);
    short4 o;
    o.x = f2bf(v.x); o.y = f2bf(v.y); o.z = f2bf(v.z); o.w = f2bf(v.w);
    *(short4*)(out + i) = o;
  }
}

// ---------------- QKV projection GEMM (m97 structure) ----------------
// Q,K written [B,H,T,Dh]; V written TRANSPOSED [B,H,Dh,T] for attention.
// T1: XCD-aware bm remap — grid.x=64, XCD ≈ blockIdx.x%8; the 8x8 transpose
// gives each XCD 8 contiguous A-panels (2MB, L2-resident across bn sweeps).
__global__ __launch_bounds__(256) void gemm_qkv(const short* __restrict__ A,
                                                const short* __restrict__ Bw,
                                                short* __restrict__ Qb,
                                                short* __restrict__ Kb,
                                                short* __restrict__ Vb) {
  const int K = CDIM;
  __shared__ __attribute__((aligned(16))) short As[128 * 32];
  __shared__ __attribute__((aligned(16))) short Bs[128 * 32];
  int tid = threadIdx.x;
  int bid = blockIdx.x;
  int bm = ((bid & 7) << 3) | (bid >> 3);   // bijective on [0,64)
  int bn = blockIdx.y;
  int lane = tid & 63, wid = tid >> 6;
  int wr = wid >> 1, wc = wid & 1;
  int la = lane & 15, lg = lane >> 4;

  const short* Ab = A + (size_t)bm * 128 * K;
  const short* Bb = Bw + (size_t)bn * 128 * K;

  f32x4 acc[4][4];
#pragma unroll
  for (int m = 0; m < 4; m++)
#pragma unroll
    for (int n = 0; n < 4; n++) acc[m][n] = (f32x4){0.f, 0.f, 0.f, 0.f};

  int c0 = tid, c1 = tid + 256;
  for (int k0 = 0; k0 < K; k0 += 32) {
    GLOAD_LDS16(Ab + (c0 >> 2) * K + k0 + (c0 & 3) * 8, &As[c0 * 8]);
    GLOAD_LDS16(Ab + (c1 >> 2) * K + k0 + (c1 & 3) * 8, &As[c1 * 8]);
    GLOAD_LDS16(Bb + (c0 >> 2) * K + k0 + (c0 & 3) * 8, &Bs[c0 * 8]);
    GLOAD_LDS16(Bb + (c1 >> 2) * K + k0 + (c1 & 3) * 8, &Bs[c1 * 8]);
    __syncthreads();
    bf16x8 af[4], bfr[4];
#pragma unroll
    for (int m = 0; m < 4; m++)
      af[m] = *(const bf16x8*)&As[(wr * 64 + m * 16 + la) * 32 + lg * 8];
#pragma unroll
    for (int n = 0; n < 4; n++)
      bfr[n] = *(const bf16x8*)&Bs[(wc * 64 + n * 16 + la) * 32 + lg * 8];
#pragma unroll
    for (int m = 0; m < 4; m++)
#pragma unroll
      for (int n = 0; n < 4; n++)
        acc[m][n] = __builtin_amdgcn_mfma_f32_16x16x32_bf16(af[m], bfr[n],
                                                            acc[m][n], 0, 0, 0);
    __syncthreads();
  }

#pragma unroll
  for (int m = 0; m < 4; m++) {
    int rbase = bm * 128 + wr * 64 + m * 16 + lg * 4;
    int b = rbase >> 11;
    int tb = rbase & 2047;
#pragma unroll
    for (int n = 0; n < 4; n++) {
      int col = bn * 128 + wc * 64 + n * 16 + la;
      int which = col >> 10;
      int h = (col >> 6) & 15;
      int d = col & 63;
      if (which == 2) {
        // V^T: [B,H,Dh,T] — 4 consecutive t at fixed d -> one 8B store
        short4 o4;
        o4.x = f2bf(acc[m][n][0]); o4.y = f2bf(acc[m][n][1]);
        o4.z = f2bf(acc[m][n][2]); o4.w = f2bf(acc[m][n][3]);
        *(short4*)&Vb[((size_t)(b * 16 + h) * 64 + d) * TT + tb] = o4;
      } else {
        short* dst = (which == 0) ? Qb : Kb;
        float sc = (which == 0) ? QSCALE : 1.0f;
        size_t base = ((size_t)(b * 16 + h) * TT) * 64 + d;
#pragma unroll
        for (int r = 0; r < 4; r++)
          dst[base + (size_t)(tb + r) * 64] = f2bf(acc[m][n][r] * sc);
      }
    }
  }
}

// ---------------- causal flash attention (32x32 swapped-QK, in-reg softmax) --
// Q,K: [B,H,T,64] (Q pre-scaled by 0.125*log2e). V: [B,H,64,T] (transposed).
// Out: [B,T,H*64] bf16.
// Block: 256 thr = 4 waves, QBLK=128 (32 q-rows/wave), KVBLK=64.
// NOTE: no min-waves clause — (256,4) capped regs at 64 VGPR + 64 AGPR and
// spilled (R3 counters: VGPR_Count=64, WRITE_SIZE 23.5MB vs 16MB output).
__global__ __launch_bounds__(256) void attn_fwd2(const short* __restrict__ Qb,
                                                 const short* __restrict__ Kb,
                                                 const short* __restrict__ Vtg,
                                                 short* __restrict__ Ob) {
  // stage: Ks[64][64] + Vs[64][64] swizzled (16KB); epilogue: 4x [32][80] (20KB)
  __shared__ __attribute__((aligned(16))) short lds[10240];
  short* Ks = lds;
  short* Vs = lds + 4096;

  int tid = threadIdx.x, lane = tid & 63, w = tid >> 6;
  int l31 = lane & 31, hi = lane >> 5, l7 = lane & 7;
  int gid = blockIdx.x;
  int qt = 15 - (gid & 15);           // longest blocks first
  int bh = gid >> 4;
  int q0 = qt * 128;
  int qw = q0 + w * 32;               // wave's q base
  int qg = qw + l31;                  // this lane's q row

  const short* Qh = Qb + (size_t)bh * TT * 64;
  const short* Kh = Kb + (size_t)bh * TT * 64;
  const short* Vh = Vtg + (size_t)bh * 64 * TT;

  // Q fragments: lane holds Q[qg][c*16 + hi*8 .. +7] for c=0..3
  bf16x8 q[4];
#pragma unroll
  for (int c = 0; c < 4; c++)
    q[c] = *(const bf16x8*)(Qh + (size_t)qg * 64 + c * 16 + hi * 8);

  f32x16 o0, o1;
#pragma unroll
  for (int r = 0; r < 16; r++) { o0[r] = 0.f; o1[r] = 0.f; }
  float m = -1e30f, lsum = 0.f;

  int nt = 2 * qt + 2;
  // staging assignment: 2 chunks/thread per buffer; row=c>>3, chunk=c&7
  int c0 = tid, c1 = tid + 256;
  int r0 = c0 >> 3, cc0 = c0 & 7;
  int r1 = c1 >> 3, cc1 = c1 & 7;

  bf16x8 kr0, kr1, vr0, vr1;
  kr0 = *(const bf16x8*)(Kh + (size_t)r0 * 64 + cc0 * 8);
  kr1 = *(const bf16x8*)(Kh + (size_t)r1 * 64 + cc1 * 8);
  vr0 = *(const bf16x8*)(Vh + (size_t)r0 * TT + cc0 * 8);
  vr1 = *(const bf16x8*)(Vh + (size_t)r1 * TT + cc1 * 8);

  for (int it = 0; it < nt; it++) {
    int kv0 = it * 64;
    __syncthreads();   // previous tile's LDS reads complete
    *(bf16x8*)&Ks[r0 * 64 + ((cc0 ^ (r0 & 7)) * 8)] = kr0;
    *(bf16x8*)&Ks[r1 * 64 + ((cc1 ^ (r1 & 7)) * 8)] = kr1;
    *(bf16x8*)&Vs[r0 * 64 + ((cc0 ^ (r0 & 7)) * 8)] = vr0;
    *(bf16x8*)&Vs[r1 * 64 + ((cc1 ^ (r1 & 7)) * 8)] = vr1;
    __syncthreads();   // staging visible
    if (it + 1 < nt) { // T14: issue next tile's loads; latency hides under compute
      int kn = kv0 + 64;
      kr0 = *(const bf16x8*)(Kh + (size_t)(kn + r0) * 64 + cc0 * 8);
      kr1 = *(const bf16x8*)(Kh + (size_t)(kn + r1) * 64 + cc1 * 8);
      vr0 = *(const bf16x8*)(Vh + (size_t)r0 * TT + kn + cc0 * 8);
      vr1 = *(const bf16x8*)(Vh + (size_t)r1 * TT + kn + cc1 * 8);
    }
    if (kv0 <= qw + 31) {   // wave-uniform: this wave has unmasked work here
      // ---- S^T = K · Q^T : col=q(lane&31), rows=k ----
      f32x16 st0, st1;
#pragma unroll
      for (int r = 0; r < 16; r++) { st0[r] = 0.f; st1[r] = 0.f; }
#pragma unroll
      for (int c = 0; c < 4; c++) {
        int cc = c * 2 + hi;
        bf16x8 kf0 = *(const bf16x8*)&Ks[l31 * 64 + ((cc ^ l7) * 8)];
        bf16x8 kf1 = *(const bf16x8*)&Ks[(32 + l31) * 64 + ((cc ^ l7) * 8)];
        st0 = __builtin_amdgcn_mfma_f32_32x32x16_bf16(kf0, q[c], st0, 0, 0, 0);
        st1 = __builtin_amdgcn_mfma_f32_32x32x16_bf16(kf1, q[c], st1, 0, 0, 0);
      }
      if (kv0 + 63 > qw) {  // diagonal region: causal mask
#pragma unroll
        for (int r = 0; r < 16; r++) {
          int kloc = (r & 3) + 8 * (r >> 2) + 4 * hi;
          if (kv0 + kloc > qg)      st0[r] = -1e30f;
          if (kv0 + 32 + kloc > qg) st1[r] = -1e30f;
        }
      }
      // ---- online softmax, lane-local rows (tree reductions, depth 5) ----
      float tm[16];
#pragma unroll
      for (int r = 0; r < 16; r++) tm[r] = fmaxf(st0[r], st1[r]);
#pragma unroll
      for (int s = 8; s >= 1; s >>= 1)
#pragma unroll
        for (int r = 0; r < 16; r++)
          if (r < s) tm[r] = fmaxf(tm[r], tm[r + s]);
      float pm = tm[0];
      pm = fmaxf(pm, __shfl_xor(pm, 32));
      if (!__all(pm <= m + 8.f)) {   // T13 defer-max
        float mn = fmaxf(m, pm);
        float fac = exp2f(m - mn);
        lsum *= fac;
#pragma unroll
        for (int r = 0; r < 16; r++) { o0[r] *= fac; o1[r] *= fac; }
        m = mn;
      }
      float ts[16];
#pragma unroll
      for (int r = 0; r < 16; r++) {
        st0[r] = exp2f(st0[r] - m);
        st1[r] = exp2f(st1[r] - m);
        ts[r] = st0[r] + st1[r];
      }
#pragma unroll
      for (int s = 8; s >= 1; s >>= 1)
#pragma unroll
        for (int r = 0; r < 16; r++)
          if (r < s) ts[r] += ts[r + s];
      float rs = ts[0];
      rs += __shfl_xor(rs, 32);
      lsum += rs;
      // ---- O^T += V^T · P^T  (T12: cvt_pk + permlane32_swap builds B-frag) ----
#pragma unroll
      for (int kb = 0; kb < 2; kb++) {
#pragma unroll
        for (int c2 = 0; c2 < 2; c2++) {
          float p0 = kb ? st1[8 * c2 + 0] : st0[8 * c2 + 0];
          float p1 = kb ? st1[8 * c2 + 1] : st0[8 * c2 + 1];
          float p2 = kb ? st1[8 * c2 + 2] : st0[8 * c2 + 2];
          float p3 = kb ? st1[8 * c2 + 3] : st0[8 * c2 + 3];
          float p4 = kb ? st1[8 * c2 + 4] : st0[8 * c2 + 4];
          float p5 = kb ? st1[8 * c2 + 5] : st0[8 * c2 + 5];
          float p6 = kb ? st1[8 * c2 + 6] : st0[8 * c2 + 6];
          float p7 = kb ? st1[8 * c2 + 7] : st0[8 * c2 + 7];
          unsigned u0, u1, u2, u3;
          asm("v_cvt_pk_bf16_f32 %0, %1, %2" : "=v"(u0) : "v"(p0), "v"(p1));
          asm("v_cvt_pk_bf16_f32 %0, %1, %2" : "=v"(u1) : "v"(p2), "v"(p3));
          asm("v_cvt_pk_bf16_f32 %0, %1, %2" : "=v"(u2) : "v"(p4), "v"(p5));
          asm("v_cvt_pk_bf16_f32 %0, %1, %2" : "=v"(u3) : "v"(p6), "v"(p7));
          asm volatile("v_permlane32_swap_b32 %0, %1" : "+v"(u0), "+v"(u2));
          asm volatile("v_permlane32_swap_b32 %0, %1" : "+v"(u1), "+v"(u3));
          union { unsigned u[4]; bf16x8 v; } pa;
          pa.u[0] = u0; pa.u[1] = u1; pa.u[2] = u2; pa.u[3] = u3;
          int ccv = kb * 4 + c2 * 2 + hi;
          bf16x8 vf0 = *(const bf16x8*)&Vs[l31 * 64 + ((ccv ^ l7) * 8)];
          bf16x8 vf1 = *(const bf16x8*)&Vs[(32 + l31) * 64 + ((ccv ^ l7) * 8)];
          o0 = __builtin_amdgcn_mfma_f32_32x32x16_bf16(vf0, pa.v, o0, 0, 0, 0);
          o1 = __builtin_amdgcn_mfma_f32_32x32x16_bf16(vf1, pa.v, o1, 0, 0, 0);
        }
      }
    }
  }

  // ---- epilogue: transpose O^T -> O via per-wave LDS area [32 q][80] ----
  __syncthreads();
  short* Os = lds + w * (32 * 80);
  float inv = 1.f / lsum;
#pragma unroll
  for (int k = 0; k < 4; k++) {
    // regs 4k..4k+3 map to consecutive d = 8k+4*hi .. +3
    float a0 = o0[4 * k + 0] * inv, a1 = o0[4 * k + 1] * inv;
    float a2 = o0[4 * k + 2] * inv, a3 = o0[4 * k + 3] * inv;
    float b0 = o1[4 * k + 0] * inv, b1 = o1[4 * k + 1] * inv;
    float b2 = o1[4 * k + 2] * inv, b3 = o1[4 * k + 3] * inv;
    unsigned w0, w1, w2, w3;
    asm("v_cvt_pk_bf16_f32 %0, %1, %2" : "=v"(w0) : "v"(a0), "v"(a1));
    asm("v_cvt_pk_bf16_f32 %0, %1, %2" : "=v"(w1) : "v"(a2), "v"(a3));
    asm("v_cvt_pk_bf16_f32 %0, %1, %2" : "=v"(w2) : "v"(b0), "v"(b1));
    asm("v_cvt_pk_bf16_f32 %0, %1, %2" : "=v"(w3) : "v"(b2), "v"(b3));
    int d = 8 * k + 4 * hi;
    uint2 pa; pa.x = w0; pa.y = w1;
    uint2 pb; pb.x = w2; pb.y = w3;
    *(uint2*)&Os[l31 * 80 + d] = pa;
    *(uint2*)&Os[l31 * 80 + 32 + d] = pb;
  }
  __syncthreads();
  int b = bh >> 4, h = bh & 15;
#pragma unroll
  for (int pass = 0; pass < 4; pass++) {
    int qr = pass * 8 + (lane >> 3);
    int cc = lane & 7;
    bf16x8 v = *(const bf16x8*)&Os[qr * 80 + cc * 8];
    *(bf16x8*)&Ob[((size_t)(b * TT + q0 + w * 32 + qr)) * CDIM + h * 64 + cc * 8] = v;
  }
}

// ---------------- output projection GEMM ----------------
__global__ __launch_bounds__(256) void gemm_out(const short* __restrict__ A,
                                                const short* __restrict__ Bw,
                                                float* __restrict__ C) {
  const int K = CDIM;
  __shared__ __attribute__((aligned(16))) short As[128 * 32];
  __shared__ __attribute__((aligned(16))) short Bs[128 * 32];
  int tid = threadIdx.x;
  int bid = blockIdx.x;
  int bm = ((bid & 7) << 3) | (bid >> 3);   // T1: bijective on [0,64)
  int bn = blockIdx.y;
  int lane = tid & 63, wid = tid >> 6;
  int wr = wid >> 1, wc = wid & 1;
  int la = lane & 15, lg = lane >> 4;

  const short* Ab = A + (size_t)bm * 128 * K;
  const short* Bb = Bw + (size_t)bn * 128 * K;

  f32x4 acc[4][4];
#pragma unroll
  for (int m = 0; m < 4; m++)
#pragma unroll
    for (int n = 0; n < 4; n++) acc[m][n] = (f32x4){0.f, 0.f, 0.f, 0.f};

  int c0 = tid, c1 = tid + 256;
  for (int k0 = 0; k0 < K; k0 += 32) {
    GLOAD_LDS16(Ab + (c0 >> 2) * K + k0 + (c0 & 3) * 8, &As[c0 * 8]);
    GLOAD_LDS16(Ab + (c1 >> 2) * K + k0 + (c1 & 3) * 8, &As[c1 * 8]);
    GLOAD_LDS16(Bb + (c0 >> 2) * K + k0 + (c0 & 3) * 8, &Bs[c0 * 8]);
    GLOAD_LDS16(Bb + (c1 >> 2) * K + k0 + (c1 & 3) * 8, &Bs[c1 * 8]);
    __syncthreads();
    bf16x8 af[4], bfr[4];
#pragma unroll
    for (int m = 0; m < 4; m++)
      af[m] = *(const bf16x8*)&As[(wr * 64 + m * 16 + la) * 32 + lg * 8];
#pragma unroll
    for (int n = 0; n < 4; n++)
      bfr[n] = *(const bf16x8*)&Bs[(wc * 64 + n * 16 + la) * 32 + lg * 8];
#pragma unroll
    for (int m = 0; m < 4; m++)
#pragma unroll
      for (int n = 0; n < 4; n++)
        acc[m][n] = __builtin_amdgcn_mfma_f32_16x16x32_bf16(af[m], bfr[n],
                                                            acc[m][n], 0, 0, 0);
    __syncthreads();
  }

#pragma unroll
  for (int m = 0; m < 4; m++) {
    int rbase = bm * 128 + wr * 64 + m * 16 + lg * 4;
#pragma unroll
    for (int n = 0; n < 4; n++) {
      int col = bn * 128 + wc * 64 + n * 16 + la;
#pragma unroll
      for (int r = 0; r < 4; r++)
        C[(size_t)(rbase + r) * CDIM + col] = acc[m][n][r];
    }
  }
}

extern "C" void kernel_launch(void* const* d_in, const int* in_sizes, int n_in,
                              void* d_out, int out_size, void* d_ws, size_t ws_size,
                              hipStream_t stream) {
  const float* x    = (const float*)d_in[0];
  const float* wqkv = (const float*)d_in[1];
  const float* wo   = (const float*)d_in[2];
  float* out = (float*)d_out;

  char* ws = (char*)d_ws;
  short* xb  = (short*)(ws);
  short* wqb = (short*)(ws + (size_t)(16 << 20));
  short* wob = (short*)(ws + (size_t)(22 << 20));
  short* Qb  = (short*)(ws + (size_t)(24 << 20));
  short* Kb  = (short*)(ws + (size_t)(40 << 20));
  short* Vb  = (short*)(ws + (size_t)(56 << 20));   // V^T layout [B,H,Dh,T]
  short* Ob  = (short*)(ws + (size_t)(72 << 20));

  conv_bf16<<<8192, 256, 0, stream>>>(x, xb, BTROWS * CDIM);
  conv_bf16<<<3072, 256, 0, stream>>>(wqkv, wqb, NQKV * CDIM);
  conv_bf16<<<1024, 256, 0, stream>>>(wo, wob, CDIM * CDIM);

  gemm_qkv<<<dim3(BTROWS / 128, NQKV / 128), 256, 0, stream>>>(xb, wqb, Qb, Kb, Vb);
  attn_fwd2<<<NBATCH * 16 * (TT / 128), 256, 0, stream>>>(Qb, Kb, Vb, Ob);
  gemm_out<<<dim3(BTROWS / 128, CDIM / 128), 256, 0, stream>>>(Ob, wob, out);
}

// Round 11
// 310.080 us; speedup vs baseline: 1.0718x; 1.0718x over previous
//
#include <hip/hip_runtime.h>
#include <hip/hip_bf16.h>
#include <cstdint>

// Problem constants: B=4, T=2048, D_MODEL=1024, H=16, Dh=64
#define TT      2048
#define NBATCH  4
#define BTROWS  8192        // B*T
#define CDIM    1024
#define NQKV    3072
// Q pre-scale: 1/sqrt(64) * log2(e)  (so attention uses exp2)
#define QSCALE  0.18033688011112042f

using bf16x8 = __attribute__((ext_vector_type(8))) short;
using f32x4  = __attribute__((ext_vector_type(4))) float;
using f32x16 = __attribute__((ext_vector_type(16))) float;

#define GLOAD_LDS16(g, l)                                                     \
  __builtin_amdgcn_global_load_lds(                                           \
      (const __attribute__((address_space(1))) unsigned int*)(g),             \
      (__attribute__((address_space(3))) unsigned int*)(l), 16, 0, 0)

__device__ inline short f2bf(float f) {
  unsigned u = __builtin_bit_cast(unsigned, f);
  u += 0x7FFF + ((u >> 16) & 1);   // RNE
  return (short)(u >> 16);
}

// ---------------- fp32 -> bf16 conversion ----------------
__global__ __launch_bounds__(256) void conv_bf16(const float* __restrict__ in,
                                                 short* __restrict__ out, int n) {
  int i = (blockIdx.x * 256 + threadIdx.x) * 4;
  if (i + 3 < n) {
    float4 v = *(const float4*)(in + i);
    short4 o;
    o.x = f2bf(v.x); o.y = f2bf(v.y); o.z = f2bf(v.z); o.w = f2bf(v.w);
    *(short4*)(out + i) = o;
  }
}

// ---------------- QKV projection GEMM (m97 structure) ----------------
// Q,K written [B,H,T,Dh]; V written TRANSPOSED [B,H,Dh,T] for attention.
// T1: XCD-aware bm remap — grid.x=64, XCD ≈ blockIdx.x%8; the 8x8 transpose
// gives each XCD 8 contiguous A-panels (2MB, L2-resident across bn sweeps).
__global__ __launch_bounds__(256) void gemm_qkv(const short* __restrict__ A,
                                                const short* __restrict__ Bw,
                                                short* __restrict__ Qb,
                                                short* __restrict__ Kb,
                                                short* __restrict__ Vb) {
  const int K = CDIM;
  __shared__ __attribute__((aligned(16))) short As[128 * 32];
  __shared__ __attribute__((aligned(16))) short Bs[128 * 32];
  int tid = threadIdx.x;
  int bid = blockIdx.x;
  int bm = ((bid & 7) << 3) | (bid >> 3);   // bijective on [0,64)
  int bn = blockIdx.y;
  int lane = tid & 63, wid = tid >> 6;
  int wr = wid >> 1, wc = wid & 1;
  int la = lane & 15, lg = lane >> 4;

  const short* Ab = A + (size_t)bm * 128 * K;
  const short* Bb = Bw + (size_t)bn * 128 * K;

  f32x4 acc[4][4];
#pragma unroll
  for (int m = 0; m < 4; m++)
#pragma unroll
    for (int n = 0; n < 4; n++) acc[m][n] = (f32x4){0.f, 0.f, 0.f, 0.f};

  int c0 = tid, c1 = tid + 256;
  for (int k0 = 0; k0 < K; k0 += 32) {
    GLOAD_LDS16(Ab + (c0 >> 2) * K + k0 + (c0 & 3) * 8, &As[c0 * 8]);
    GLOAD_LDS16(Ab + (c1 >> 2) * K + k0 + (c1 & 3) * 8, &As[c1 * 8]);
    GLOAD_LDS16(Bb + (c0 >> 2) * K + k0 + (c0 & 3) * 8, &Bs[c0 * 8]);
    GLOAD_LDS16(Bb + (c1 >> 2) * K + k0 + (c1 & 3) * 8, &Bs[c1 * 8]);
    __syncthreads();
    bf16x8 af[4], bfr[4];
#pragma unroll
    for (int m = 0; m < 4; m++)
      af[m] = *(const bf16x8*)&As[(wr * 64 + m * 16 + la) * 32 + lg * 8];
#pragma unroll
    for (int n = 0; n < 4; n++)
      bfr[n] = *(const bf16x8*)&Bs[(wc * 64 + n * 16 + la) * 32 + lg * 8];
#pragma unroll
    for (int m = 0; m < 4; m++)
#pragma unroll
      for (int n = 0; n < 4; n++)
        acc[m][n] = __builtin_amdgcn_mfma_f32_16x16x32_bf16(af[m], bfr[n],
                                                            acc[m][n], 0, 0, 0);
    __syncthreads();
  }

#pragma unroll
  for (int m = 0; m < 4; m++) {
    int rbase = bm * 128 + wr * 64 + m * 16 + lg * 4;
    int b = rbase >> 11;
    int tb = rbase & 2047;
#pragma unroll
    for (int n = 0; n < 4; n++) {
      int col = bn * 128 + wc * 64 + n * 16 + la;
      int which = col >> 10;
      int h = (col >> 6) & 15;
      int d = col & 63;
      if (which == 2) {
        // V^T: [B,H,Dh,T] — 4 consecutive t at fixed d -> one 8B store
        short4 o4;
        o4.x = f2bf(acc[m][n][0]); o4.y = f2bf(acc[m][n][1]);
        o4.z = f2bf(acc[m][n][2]); o4.w = f2bf(acc[m][n][3]);
        *(short4*)&Vb[((size_t)(b * 16 + h) * 64 + d) * TT + tb] = o4;
      } else {
        short* dst = (which == 0) ? Qb : Kb;
        float sc = (which == 0) ? QSCALE : 1.0f;
        size_t base = ((size_t)(b * 16 + h) * TT) * 64 + d;
#pragma unroll
        for (int r = 0; r < 4; r++)
          dst[base + (size_t)(tb + r) * 64] = f2bf(acc[m][n][r] * sc);
      }
    }
  }
}

// ---------------- causal flash attention (32x32 swapped-QK, in-reg softmax) --
// Q,K: [B,H,T,64] (Q pre-scaled by 0.125*log2e). V: [B,H,64,T] (transposed).
// Out: [B,T,H*64] bf16.
// Block: 256 thr = 4 waves, QBLK=128 (32 q-rows/wave), KVBLK=64.
// Launch-bounds A/B history:
//   (256,4): 128-reg cap -> heavy spill (WRITE 23.5MB), occ 18.7%, 126us
//   (256)  : ~168 regs, no spill (WRITE 16.4MB), occ 11.5%, 156us  <- latency-bound
//   (256,3): 170-reg cap -> no spill AND 3 blocks/CU (this round)
// NOTE: scalar cross-half reductions use __shfl_xor. A permlane32_swap
// variant with BOTH operands = same value got register-coalesced into
// `v_permlane32_swap v0,v0` (self half-swap, not a combine) -> absmax 1.3.
__global__ __launch_bounds__(256, 3) void attn_fwd2(const short* __restrict__ Qb,
                                                    const short* __restrict__ Kb,
                                                    const short* __restrict__ Vtg,
                                                    short* __restrict__ Ob) {
  // stage: Ks[64][64] + Vs[64][64] swizzled (16KB); epilogue: 4x [32][80] (20KB)
  __shared__ __attribute__((aligned(16))) short lds[10240];
  short* Ks = lds;
  short* Vs = lds + 4096;

  int tid = threadIdx.x, lane = tid & 63, w = tid >> 6;
  int l31 = lane & 31, hi = lane >> 5, l7 = lane & 7;
  int gid = blockIdx.x;
  int qt = 15 - (gid & 15);           // longest blocks first
  int bh = gid >> 4;
  int q0 = qt * 128;
  int qw = q0 + w * 32;               // wave's q base
  int qg = qw + l31;                  // this lane's q row

  const short* Qh = Qb + (size_t)bh * TT * 64;
  const short* Kh = Kb + (size_t)bh * TT * 64;
  const short* Vh = Vtg + (size_t)bh * 64 * TT;

  // Q fragments: lane holds Q[qg][c*16 + hi*8 .. +7] for c=0..3
  bf16x8 q[4];
#pragma unroll
  for (int c = 0; c < 4; c++)
    q[c] = *(const bf16x8*)(Qh + (size_t)qg * 64 + c * 16 + hi * 8);

  f32x16 o0, o1;
#pragma unroll
  for (int r = 0; r < 16; r++) { o0[r] = 0.f; o1[r] = 0.f; }
  float m = -1e30f, lsum = 0.f;

  int nt = 2 * qt + 2;
  // staging assignment: 2 chunks/thread per buffer; row=c>>3, chunk=c&7
  int c0 = tid, c1 = tid + 256;
  int r0 = c0 >> 3, cc0 = c0 & 7;
  int r1 = c1 >> 3, cc1 = c1 & 7;

  bf16x8 kr0, kr1, vr0, vr1;
  kr0 = *(const bf16x8*)(Kh + (size_t)r0 * 64 + cc0 * 8);
  kr1 = *(const bf16x8*)(Kh + (size_t)r1 * 64 + cc1 * 8);
  vr0 = *(const bf16x8*)(Vh + (size_t)r0 * TT + cc0 * 8);
  vr1 = *(const bf16x8*)(Vh + (size_t)r1 * TT + cc1 * 8);

  for (int it = 0; it < nt; it++) {
    int kv0 = it * 64;
    __syncthreads();   // previous tile's LDS reads complete
    *(bf16x8*)&Ks[r0 * 64 + ((cc0 ^ (r0 & 7)) * 8)] = kr0;
    *(bf16x8*)&Ks[r1 * 64 + ((cc1 ^ (r1 & 7)) * 8)] = kr1;
    *(bf16x8*)&Vs[r0 * 64 + ((cc0 ^ (r0 & 7)) * 8)] = vr0;
    *(bf16x8*)&Vs[r1 * 64 + ((cc1 ^ (r1 & 7)) * 8)] = vr1;
    __syncthreads();   // staging visible
    if (it + 1 < nt) { // T14: issue next tile's loads; latency hides under compute
      int kn = kv0 + 64;
      kr0 = *(const bf16x8*)(Kh + (size_t)(kn + r0) * 64 + cc0 * 8);
      kr1 = *(const bf16x8*)(Kh + (size_t)(kn + r1) * 64 + cc1 * 8);
      vr0 = *(const bf16x8*)(Vh + (size_t)r0 * TT + kn + cc0 * 8);
      vr1 = *(const bf16x8*)(Vh + (size_t)r1 * TT + kn + cc1 * 8);
    }
    if (kv0 <= qw + 31) {   // wave-uniform: this wave has unmasked work here
      // ---- S^T = K · Q^T : col=q(lane&31), rows=k ----
      f32x16 st0, st1;
#pragma unroll
      for (int r = 0; r < 16; r++) { st0[r] = 0.f; st1[r] = 0.f; }
#pragma unroll
      for (int c = 0; c < 4; c++) {
        int cc = c * 2 + hi;
        bf16x8 kf0 = *(const bf16x8*)&Ks[l31 * 64 + ((cc ^ l7) * 8)];
        bf16x8 kf1 = *(const bf16x8*)&Ks[(32 + l31) * 64 + ((cc ^ l7) * 8)];
        st0 = __builtin_amdgcn_mfma_f32_32x32x16_bf16(kf0, q[c], st0, 0, 0, 0);
        st1 = __builtin_amdgcn_mfma_f32_32x32x16_bf16(kf1, q[c], st1, 0, 0, 0);
      }
      if (kv0 + 63 > qw) {  // diagonal region: causal mask
#pragma unroll
        for (int r = 0; r < 16; r++) {
          int kloc = (r & 3) + 8 * (r >> 2) + 4 * hi;
          if (kv0 + kloc > qg)      st0[r] = -1e30f;
          if (kv0 + 32 + kloc > qg) st1[r] = -1e30f;
        }
      }
      // ---- online softmax, lane-local rows (tree reductions, depth 5) ----
      float tm[16];
#pragma unroll
      for (int r = 0; r < 16; r++) tm[r] = fmaxf(st0[r], st1[r]);
#pragma unroll
      for (int s = 8; s >= 1; s >>= 1)
#pragma unroll
        for (int r = 0; r < 16; r++)
          if (r < s) tm[r] = fmaxf(tm[r], tm[r + s]);
      float pm = tm[0];
      pm = fmaxf(pm, __shfl_xor(pm, 32));
      if (!__all(pm <= m + 8.f)) {   // T13 defer-max
        float mn = fmaxf(m, pm);
        float fac = exp2f(m - mn);
        lsum *= fac;
#pragma unroll
        for (int r = 0; r < 16; r++) { o0[r] *= fac; o1[r] *= fac; }
        m = mn;
      }
      float ts[16];
#pragma unroll
      for (int r = 0; r < 16; r++) {
        st0[r] = exp2f(st0[r] - m);
        st1[r] = exp2f(st1[r] - m);
        ts[r] = st0[r] + st1[r];
      }
#pragma unroll
      for (int s = 8; s >= 1; s >>= 1)
#pragma unroll
        for (int r = 0; r < 16; r++)
          if (r < s) ts[r] += ts[r + s];
      float rs = ts[0];
      rs += __shfl_xor(rs, 32);
      lsum += rs;
      // ---- O^T += V^T · P^T  (T12: cvt_pk + permlane32_swap builds B-frag) ----
#pragma unroll
      for (int kb = 0; kb < 2; kb++) {
#pragma unroll
        for (int c2 = 0; c2 < 2; c2++) {
          float p0 = kb ? st1[8 * c2 + 0] : st0[8 * c2 + 0];
          float p1 = kb ? st1[8 * c2 + 1] : st0[8 * c2 + 1];
          float p2 = kb ? st1[8 * c2 + 2] : st0[8 * c2 + 2];
          float p3 = kb ? st1[8 * c2 + 3] : st0[8 * c2 + 3];
          float p4 = kb ? st1[8 * c2 + 4] : st0[8 * c2 + 4];
          float p5 = kb ? st1[8 * c2 + 5] : st0[8 * c2 + 5];
          float p6 = kb ? st1[8 * c2 + 6] : st0[8 * c2 + 6];
          float p7 = kb ? st1[8 * c2 + 7] : st0[8 * c2 + 7];
          unsigned u0, u1, u2, u3;
          asm("v_cvt_pk_bf16_f32 %0, %1, %2" : "=v"(u0) : "v"(p0), "v"(p1));
          asm("v_cvt_pk_bf16_f32 %0, %1, %2" : "=v"(u1) : "v"(p2), "v"(p3));
          asm("v_cvt_pk_bf16_f32 %0, %1, %2" : "=v"(u2) : "v"(p4), "v"(p5));
          asm("v_cvt_pk_bf16_f32 %0, %1, %2" : "=v"(u3) : "v"(p6), "v"(p7));
          asm volatile("v_permlane32_swap_b32 %0, %1" : "+v"(u0), "+v"(u2));
          asm volatile("v_permlane32_swap_b32 %0, %1" : "+v"(u1), "+v"(u3));
          union { unsigned u[4]; bf16x8 v; } pa;
          pa.u[0] = u0; pa.u[1] = u1; pa.u[2] = u2; pa.u[3] = u3;
          int ccv = kb * 4 + c2 * 2 + hi;
          bf16x8 vf0 = *(const bf16x8*)&Vs[l31 * 64 + ((ccv ^ l7) * 8)];
          bf16x8 vf1 = *(const bf16x8*)&Vs[(32 + l31) * 64 + ((ccv ^ l7) * 8)];
          o0 = __builtin_amdgcn_mfma_f32_32x32x16_bf16(vf0, pa.v, o0, 0, 0, 0);
          o1 = __builtin_amdgcn_mfma_f32_32x32x16_bf16(vf1, pa.v, o1, 0, 0, 0);
        }
      }
    }
  }

  // ---- epilogue: transpose O^T -> O via per-wave LDS area [32 q][80] ----
  __syncthreads();
  short* Os = lds + w * (32 * 80);
  float inv = 1.f / lsum;
#pragma unroll
  for (int k = 0; k < 4; k++) {
    // regs 4k..4k+3 map to consecutive d = 8k+4*hi .. +3
    float a0 = o0[4 * k + 0] * inv, a1 = o0[4 * k + 1] * inv;
    float a2 = o0[4 * k + 2] * inv, a3 = o0[4 * k + 3] * inv;
    float b0 = o1[4 * k + 0] * inv, b1 = o1[4 * k + 1] * inv;
    float b2 = o1[4 * k + 2] * inv, b3 = o1[4 * k + 3] * inv;
    unsigned w0, w1, w2, w3;
    asm("v_cvt_pk_bf16_f32 %0, %1, %2" : "=v"(w0) : "v"(a0), "v"(a1));
    asm("v_cvt_pk_bf16_f32 %0, %1, %2" : "=v"(w1) : "v"(a2), "v"(a3));
    asm("v_cvt_pk_bf16_f32 %0, %1, %2" : "=v"(w2) : "v"(b0), "v"(b1));
    asm("v_cvt_pk_bf16_f32 %0, %1, %2" : "=v"(w3) : "v"(b2), "v"(b3));
    int d = 8 * k + 4 * hi;
    uint2 pa; pa.x = w0; pa.y = w1;
    uint2 pb; pb.x = w2; pb.y = w3;
    *(uint2*)&Os[l31 * 80 + d] = pa;
    *(uint2*)&Os[l31 * 80 + 32 + d] = pb;
  }
  __syncthreads();
  int b = bh >> 4, h = bh & 15;
#pragma unroll
  for (int pass = 0; pass < 4; pass++) {
    int qr = pass * 8 + (lane >> 3);
    int cc = lane & 7;
    bf16x8 v = *(const bf16x8*)&Os[qr * 80 + cc * 8];
    *(bf16x8*)&Ob[((size_t)(b * TT + q0 + w * 32 + qr)) * CDIM + h * 64 + cc * 8] = v;
  }
}

// ---------------- output projection GEMM ----------------
__global__ __launch_bounds__(256) void gemm_out(const short* __restrict__ A,
                                                const short* __restrict__ Bw,
                                                float* __restrict__ C) {
  const int K = CDIM;
  __shared__ __attribute__((aligned(16))) short As[128 * 32];
  __shared__ __attribute__((aligned(16))) short Bs[128 * 32];
  int tid = threadIdx.x;
  int bid = blockIdx.x;
  int bm = ((bid & 7) << 3) | (bid >> 3);   // T1: bijective on [0,64)
  int bn = blockIdx.y;
  int lane = tid & 63, wid = tid >> 6;
  int wr = wid >> 1, wc = wid & 1;
  int la = lane & 15, lg = lane >> 4;

  const short* Ab = A + (size_t)bm * 128 * K;
  const short* Bb = Bw + (size_t)bn * 128 * K;

  f32x4 acc[4][4];
#pragma unroll
  for (int m = 0; m < 4; m++)
#pragma unroll
    for (int n = 0; n < 4; n++) acc[m][n] = (f32x4){0.f, 0.f, 0.f, 0.f};

  int c0 = tid, c1 = tid + 256;
  for (int k0 = 0; k0 < K; k0 += 32) {
    GLOAD_LDS16(Ab + (c0 >> 2) * K + k0 + (c0 & 3) * 8, &As[c0 * 8]);
    GLOAD_LDS16(Ab + (c1 >> 2) * K + k0 + (c1 & 3) * 8, &As[c1 * 8]);
    GLOAD_LDS16(Bb + (c0 >> 2) * K + k0 + (c0 & 3) * 8, &Bs[c0 * 8]);
    GLOAD_LDS16(Bb + (c1 >> 2) * K + k0 + (c1 & 3) * 8, &Bs[c1 * 8]);
    __syncthreads();
    bf16x8 af[4], bfr[4];
#pragma unroll
    for (int m = 0; m < 4; m++)
      af[m] = *(const bf16x8*)&As[(wr * 64 + m * 16 + la) * 32 + lg * 8];
#pragma unroll
    for (int n = 0; n < 4; n++)
      bfr[n] = *(const bf16x8*)&Bs[(wc * 64 + n * 16 + la) * 32 + lg * 8];
#pragma unroll
    for (int m = 0; m < 4; m++)
#pragma unroll
      for (int n = 0; n < 4; n++)
        acc[m][n] = __builtin_amdgcn_mfma_f32_16x16x32_bf16(af[m], bfr[n],
                                                            acc[m][n], 0, 0, 0);
    __syncthreads();
  }

#pragma unroll
  for (int m = 0; m < 4; m++) {
    int rbase = bm * 128 + wr * 64 + m * 16 + lg * 4;
#pragma unroll
    for (int n = 0; n < 4; n++) {
      int col = bn * 128 + wc * 64 + n * 16 + la;
#pragma unroll
      for (int r = 0; r < 4; r++)
        C[(size_t)(rbase + r) * CDIM + col] = acc[m][n][r];
    }
  }
}

extern "C" void kernel_launch(void* const* d_in, const int* in_sizes, int n_in,
                              void* d_out, int out_size, void* d_ws, size_t ws_size,
                              hipStream_t stream) {
  const float* x    = (const float*)d_in[0];
  const float* wqkv = (const float*)d_in[1];
  const float* wo   = (const float*)d_in[2];
  float* out = (float*)d_out;

  char* ws = (char*)d_ws;
  short* xb  = (short*)(ws);
  short* wqb = (short*)(ws + (size_t)(16 << 20));
  short* wob = (short*)(ws + (size_t)(22 << 20));
  short* Qb  = (short*)(ws + (size_t)(24 << 20));
  short* Kb  = (short*)(ws + (size_t)(40 << 20));
  short* Vb  = (short*)(ws + (size_t)(56 << 20));   // V^T layout [B,H,Dh,T]
  short* Ob  = (short*)(ws + (size_t)(72 << 20));

  conv_bf16<<<8192, 256, 0, stream>>>(x, xb, BTROWS * CDIM);
  conv_bf16<<<3072, 256, 0, stream>>>(wqkv, wqb, NQKV * CDIM);
  conv_bf16<<<1024, 256, 0, stream>>>(wo, wob, CDIM * CDIM);

  gemm_qkv<<<dim3(BTROWS / 128, NQKV / 128), 256, 0, stream>>>(xb, wqb, Qb, Kb, Vb);
  attn_fwd2<<<NBATCH * 16 * (TT / 128), 256, 0, stream>>>(Qb, Kb, Vb, Ob);
  gemm_out<<<dim3(BTROWS / 128, CDIM / 128), 256, 0, stream>>>(Ob, wob, out);
}

// Round 12
// 308.201 us; speedup vs baseline: 1.0784x; 1.0061x over previous
//
#include <hip/hip_runtime.h>
#include <hip/hip_bf16.h>
#include <cstdint>

// Problem constants: B=4, T=2048, D_MODEL=1024, H=16, Dh=64
#define TT      2048
#define NBATCH  4
#define BTROWS  8192        // B*T
#define CDIM    1024
#define NQKV    3072
// Q pre-scale: 1/sqrt(64) * log2(e)  (so attention uses exp2)
#define QSCALE  0.18033688011112042f

using bf16x8 = __attribute__((ext_vector_type(8))) short;
using f32x4  = __attribute__((ext_vector_type(4))) float;
using f32x16 = __attribute__((ext_vector_type(16))) float;

#define GLOAD_LDS16(g, l)                                                     \
  __builtin_amdgcn_global_load_lds(                                           \
      (const __attribute__((address_space(1))) unsigned int*)(g),             \
      (__attribute__((address_space(3))) unsigned int*)(l), 16, 0, 0)

__device__ inline short f2bf(float f) {
  unsigned u = __builtin_bit_cast(unsigned, f);
  u += 0x7FFF + ((u >> 16) & 1);   // RNE
  return (short)(u >> 16);
}

// ---------------- fp32 -> bf16 conversion ----------------
__global__ __launch_bounds__(256) void conv_bf16(const float* __restrict__ in,
                                                 short* __restrict__ out, int n) {
  int i = (blockIdx.x * 256 + threadIdx.x) * 4;
  if (i + 3 < n) {
    float4 v = *(const float4*)(in + i);
    short4 o;
    o.x = f2bf(v.x); o.y = f2bf(v.y); o.z = f2bf(v.z); o.w = f2bf(v.w);
    *(short4*)(out + i) = o;
  }
}

// ---------------- QKV projection GEMM (m97 structure) ----------------
// Q,K written [B,H,T,Dh]; V written TRANSPOSED [B,H,Dh,T] for attention.
// T1: XCD-aware bm remap (8x8 transpose on grid.x=64).
// R12: `which` is block-uniform (bn/8: 0-7 Q, 8-15 K, 16-23 V). Q/K blocks
// use an LDS-transpose epilogue (reuse As/Bs after K-loop): scalar 2B global
// stores at 128B stride -> per-wave [16][72] LDS tile -> coalesced 16B stores
// (wave covers 16 full 128B rows).
__global__ __launch_bounds__(256) void gemm_qkv(const short* __restrict__ A,
                                                const short* __restrict__ Bw,
                                                short* __restrict__ Qb,
                                                short* __restrict__ Kb,
                                                short* __restrict__ Vb) {
  const int K = CDIM;
  __shared__ __attribute__((aligned(16))) short smem[8192];  // As|Bs, reused by epilogue
  short* As = smem;
  short* Bs = smem + 4096;
  int tid = threadIdx.x;
  int bid = blockIdx.x;
  int bm = ((bid & 7) << 3) | (bid >> 3);   // bijective on [0,64)
  int bn = blockIdx.y;
  int lane = tid & 63, wid = tid >> 6;
  int wr = wid >> 1, wc = wid & 1;
  int la = lane & 15, lg = lane >> 4;

  const short* Ab = A + (size_t)bm * 128 * K;
  const short* Bb = Bw + (size_t)bn * 128 * K;

  f32x4 acc[4][4];
#pragma unroll
  for (int m = 0; m < 4; m++)
#pragma unroll
    for (int n = 0; n < 4; n++) acc[m][n] = (f32x4){0.f, 0.f, 0.f, 0.f};

  int c0 = tid, c1 = tid + 256;
  for (int k0 = 0; k0 < K; k0 += 32) {
    GLOAD_LDS16(Ab + (c0 >> 2) * K + k0 + (c0 & 3) * 8, &As[c0 * 8]);
    GLOAD_LDS16(Ab + (c1 >> 2) * K + k0 + (c1 & 3) * 8, &As[c1 * 8]);
    GLOAD_LDS16(Bb + (c0 >> 2) * K + k0 + (c0 & 3) * 8, &Bs[c0 * 8]);
    GLOAD_LDS16(Bb + (c1 >> 2) * K + k0 + (c1 & 3) * 8, &Bs[c1 * 8]);
    __syncthreads();
    bf16x8 af[4], bfr[4];
#pragma unroll
    for (int m = 0; m < 4; m++)
      af[m] = *(const bf16x8*)&As[(wr * 64 + m * 16 + la) * 32 + lg * 8];
#pragma unroll
    for (int n = 0; n < 4; n++)
      bfr[n] = *(const bf16x8*)&Bs[(wc * 64 + n * 16 + la) * 32 + lg * 8];
#pragma unroll
    for (int m = 0; m < 4; m++)
#pragma unroll
      for (int n = 0; n < 4; n++)
        acc[m][n] = __builtin_amdgcn_mfma_f32_16x16x32_bf16(af[m], bfr[n],
                                                            acc[m][n], 0, 0, 0);
    __syncthreads();
  }

  int colbase = bn * 128 + wc * 64;       // 64-aligned -> one head per wave
  int which = colbase >> 10;              // block-uniform
  int b = bm >> 4;

  if (which == 2) {
    // V^T: [B,H,Dh,T] — 4 consecutive t at fixed d -> one 8B store
#pragma unroll
    for (int m = 0; m < 4; m++) {
      int tb = (bm * 128 + wr * 64 + m * 16 + lg * 4) & 2047;
#pragma unroll
      for (int n = 0; n < 4; n++) {
        int col = colbase + n * 16 + la;
        int h = (col >> 6) & 15;
        int d = col & 63;
        short4 o4;
        o4.x = f2bf(acc[m][n][0]); o4.y = f2bf(acc[m][n][1]);
        o4.z = f2bf(acc[m][n][2]); o4.w = f2bf(acc[m][n][3]);
        *(short4*)&Vb[((size_t)(b * 16 + h) * 64 + d) * TT + tb] = o4;
      }
    }
  } else {
    // Q/K: LDS-transpose epilogue -> coalesced 16B row stores
    short* dst = (which == 0) ? Qb : Kb;
    float sc = (which == 0) ? QSCALE : 1.0f;
    int h = (colbase >> 6) & 15;
    size_t hbase = ((size_t)(b * 16 + h) * TT) * 64;
    short* Ls = smem + wid * (16 * 72);   // per-wave 2304B region (4x = 9216B <= 16KB)
    int rrow = lane & 15, chunk = lane >> 4;
#pragma unroll
    for (int m = 0; m < 4; m++) {
#pragma unroll
      for (int n = 0; n < 4; n++)
#pragma unroll
        for (int r = 0; r < 4; r++)
          Ls[(lg * 4 + r) * 72 + n * 16 + la] = f2bf(acc[m][n][r] * sc);
      __syncthreads();
      int t = (bm * 128 + wr * 64 + m * 16 + rrow) & 2047;
      bf16x8 v0 = *(const bf16x8*)&Ls[rrow * 72 + chunk * 16];
      bf16x8 v1 = *(const bf16x8*)&Ls[rrow * 72 + chunk * 16 + 8];
      *(bf16x8*)&dst[hbase + (size_t)t * 64 + chunk * 16] = v0;
      *(bf16x8*)&dst[hbase + (size_t)t * 64 + chunk * 16 + 8] = v1;
      __syncthreads();
    }
  }
}

// ---------------- causal flash attention (32x32 swapped-QK, in-reg softmax) --
// Q,K: [B,H,T,64] (Q pre-scaled by 0.125*log2e). V: [B,H,64,T] (transposed).
// Out: [B,T,H*64] bf16.
// Block: 256 thr = 4 waves, QBLK=128 (32 q-rows/wave), KVBLK=64.
// Launch-bounds A/B/C: (256,4)=126us spilled; (256)=156us occ 11.5%;
// (256,3)=122.6us no-spill occ 14% <- keep. R12: +T5 setprio on MFMA clusters.
// NOTE: scalar cross-half reductions use __shfl_xor. A permlane32_swap
// variant with BOTH operands = same value got register-coalesced into
// `v_permlane32_swap v0,v0` (self half-swap, not a combine) -> absmax 1.3.
__global__ __launch_bounds__(256, 3) void attn_fwd2(const short* __restrict__ Qb,
                                                    const short* __restrict__ Kb,
                                                    const short* __restrict__ Vtg,
                                                    short* __restrict__ Ob) {
  // stage: Ks[64][64] + Vs[64][64] swizzled (16KB); epilogue: 4x [32][80] (20KB)
  __shared__ __attribute__((aligned(16))) short lds[10240];
  short* Ks = lds;
  short* Vs = lds + 4096;

  int tid = threadIdx.x, lane = tid & 63, w = tid >> 6;
  int l31 = lane & 31, hi = lane >> 5, l7 = lane & 7;
  int gid = blockIdx.x;
  int qt = 15 - (gid & 15);           // longest blocks first
  int bh = gid >> 4;
  int q0 = qt * 128;
  int qw = q0 + w * 32;               // wave's q base
  int qg = qw + l31;                  // this lane's q row

  const short* Qh = Qb + (size_t)bh * TT * 64;
  const short* Kh = Kb + (size_t)bh * TT * 64;
  const short* Vh = Vtg + (size_t)bh * 64 * TT;

  // Q fragments: lane holds Q[qg][c*16 + hi*8 .. +7] for c=0..3
  bf16x8 q[4];
#pragma unroll
  for (int c = 0; c < 4; c++)
    q[c] = *(const bf16x8*)(Qh + (size_t)qg * 64 + c * 16 + hi * 8);

  f32x16 o0, o1;
#pragma unroll
  for (int r = 0; r < 16; r++) { o0[r] = 0.f; o1[r] = 0.f; }
  float m = -1e30f, lsum = 0.f;

  int nt = 2 * qt + 2;
  // staging assignment: 2 chunks/thread per buffer; row=c>>3, chunk=c&7
  int c0 = tid, c1 = tid + 256;
  int r0 = c0 >> 3, cc0 = c0 & 7;
  int r1 = c1 >> 3, cc1 = c1 & 7;

  bf16x8 kr0, kr1, vr0, vr1;
  kr0 = *(const bf16x8*)(Kh + (size_t)r0 * 64 + cc0 * 8);
  kr1 = *(const bf16x8*)(Kh + (size_t)r1 * 64 + cc1 * 8);
  vr0 = *(const bf16x8*)(Vh + (size_t)r0 * TT + cc0 * 8);
  vr1 = *(const bf16x8*)(Vh + (size_t)r1 * TT + cc1 * 8);

  for (int it = 0; it < nt; it++) {
    int kv0 = it * 64;
    __syncthreads();   // previous tile's LDS reads complete
    *(bf16x8*)&Ks[r0 * 64 + ((cc0 ^ (r0 & 7)) * 8)] = kr0;
    *(bf16x8*)&Ks[r1 * 64 + ((cc1 ^ (r1 & 7)) * 8)] = kr1;
    *(bf16x8*)&Vs[r0 * 64 + ((cc0 ^ (r0 & 7)) * 8)] = vr0;
    *(bf16x8*)&Vs[r1 * 64 + ((cc1 ^ (r1 & 7)) * 8)] = vr1;
    __syncthreads();   // staging visible
    if (it + 1 < nt) { // T14: issue next tile's loads; latency hides under compute
      int kn = kv0 + 64;
      kr0 = *(const bf16x8*)(Kh + (size_t)(kn + r0) * 64 + cc0 * 8);
      kr1 = *(const bf16x8*)(Kh + (size_t)(kn + r1) * 64 + cc1 * 8);
      vr0 = *(const bf16x8*)(Vh + (size_t)r0 * TT + kn + cc0 * 8);
      vr1 = *(const bf16x8*)(Vh + (size_t)r1 * TT + kn + cc1 * 8);
    }
    if (kv0 <= qw + 31) {   // wave-uniform: this wave has unmasked work here
      // ---- S^T = K · Q^T : col=q(lane&31), rows=k ----
      f32x16 st0, st1;
#pragma unroll
      for (int r = 0; r < 16; r++) { st0[r] = 0.f; st1[r] = 0.f; }
      __builtin_amdgcn_s_setprio(1);
#pragma unroll
      for (int c = 0; c < 4; c++) {
        int cc = c * 2 + hi;
        bf16x8 kf0 = *(const bf16x8*)&Ks[l31 * 64 + ((cc ^ l7) * 8)];
        bf16x8 kf1 = *(const bf16x8*)&Ks[(32 + l31) * 64 + ((cc ^ l7) * 8)];
        st0 = __builtin_amdgcn_mfma_f32_32x32x16_bf16(kf0, q[c], st0, 0, 0, 0);
        st1 = __builtin_amdgcn_mfma_f32_32x32x16_bf16(kf1, q[c], st1, 0, 0, 0);
      }
      __builtin_amdgcn_s_setprio(0);
      if (kv0 + 63 > qw) {  // diagonal region: causal mask
#pragma unroll
        for (int r = 0; r < 16; r++) {
          int kloc = (r & 3) + 8 * (r >> 2) + 4 * hi;
          if (kv0 + kloc > qg)      st0[r] = -1e30f;
          if (kv0 + 32 + kloc > qg) st1[r] = -1e30f;
        }
      }
      // ---- online softmax, lane-local rows (tree reductions, depth 5) ----
      float tm[16];
#pragma unroll
      for (int r = 0; r < 16; r++) tm[r] = fmaxf(st0[r], st1[r]);
#pragma unroll
      for (int s = 8; s >= 1; s >>= 1)
#pragma unroll
        for (int r = 0; r < 16; r++)
          if (r < s) tm[r] = fmaxf(tm[r], tm[r + s]);
      float pm = tm[0];
      pm = fmaxf(pm, __shfl_xor(pm, 32));
      if (!__all(pm <= m + 8.f)) {   // T13 defer-max
        float mn = fmaxf(m, pm);
        float fac = exp2f(m - mn);
        lsum *= fac;
#pragma unroll
        for (int r = 0; r < 16; r++) { o0[r] *= fac; o1[r] *= fac; }
        m = mn;
      }
      float ts[16];
#pragma unroll
      for (int r = 0; r < 16; r++) {
        st0[r] = exp2f(st0[r] - m);
        st1[r] = exp2f(st1[r] - m);
        ts[r] = st0[r] + st1[r];
      }
#pragma unroll
      for (int s = 8; s >= 1; s >>= 1)
#pragma unroll
        for (int r = 0; r < 16; r++)
          if (r < s) ts[r] += ts[r + s];
      float rs = ts[0];
      rs += __shfl_xor(rs, 32);
      lsum += rs;
      // ---- O^T += V^T · P^T  (T12: cvt_pk + permlane32_swap builds B-frag) ----
      __builtin_amdgcn_s_setprio(1);
#pragma unroll
      for (int kb = 0; kb < 2; kb++) {
#pragma unroll
        for (int c2 = 0; c2 < 2; c2++) {
          float p0 = kb ? st1[8 * c2 + 0] : st0[8 * c2 + 0];
          float p1 = kb ? st1[8 * c2 + 1] : st0[8 * c2 + 1];
          float p2 = kb ? st1[8 * c2 + 2] : st0[8 * c2 + 2];
          float p3 = kb ? st1[8 * c2 + 3] : st0[8 * c2 + 3];
          float p4 = kb ? st1[8 * c2 + 4] : st0[8 * c2 + 4];
          float p5 = kb ? st1[8 * c2 + 5] : st0[8 * c2 + 5];
          float p6 = kb ? st1[8 * c2 + 6] : st0[8 * c2 + 6];
          float p7 = kb ? st1[8 * c2 + 7] : st0[8 * c2 + 7];
          unsigned u0, u1, u2, u3;
          asm("v_cvt_pk_bf16_f32 %0, %1, %2" : "=v"(u0) : "v"(p0), "v"(p1));
          asm("v_cvt_pk_bf16_f32 %0, %1, %2" : "=v"(u1) : "v"(p2), "v"(p3));
          asm("v_cvt_pk_bf16_f32 %0, %1, %2" : "=v"(u2) : "v"(p4), "v"(p5));
          asm("v_cvt_pk_bf16_f32 %0, %1, %2" : "=v"(u3) : "v"(p6), "v"(p7));
          asm volatile("v_permlane32_swap_b32 %0, %1" : "+v"(u0), "+v"(u2));
          asm volatile("v_permlane32_swap_b32 %0, %1" : "+v"(u1), "+v"(u3));
          union { unsigned u[4]; bf16x8 v; } pa;
          pa.u[0] = u0; pa.u[1] = u1; pa.u[2] = u2; pa.u[3] = u3;
          int ccv = kb * 4 + c2 * 2 + hi;
          bf16x8 vf0 = *(const bf16x8*)&Vs[l31 * 64 + ((ccv ^ l7) * 8)];
          bf16x8 vf1 = *(const bf16x8*)&Vs[(32 + l31) * 64 + ((ccv ^ l7) * 8)];
          o0 = __builtin_amdgcn_mfma_f32_32x32x16_bf16(vf0, pa.v, o0, 0, 0, 0);
          o1 = __builtin_amdgcn_mfma_f32_32x32x16_bf16(vf1, pa.v, o1, 0, 0, 0);
        }
      }
      __builtin_amdgcn_s_setprio(0);
    }
  }

  // ---- epilogue: transpose O^T -> O via per-wave LDS area [32 q][80] ----
  __syncthreads();
  short* Os = lds + w * (32 * 80);
  float inv = 1.f / lsum;
#pragma unroll
  for (int k = 0; k < 4; k++) {
    // regs 4k..4k+3 map to consecutive d = 8k+4*hi .. +3
    float a0 = o0[4 * k + 0] * inv, a1 = o0[4 * k + 1] * inv;
    float a2 = o0[4 * k + 2] * inv, a3 = o0[4 * k + 3] * inv;
    float b0 = o1[4 * k + 0] * inv, b1 = o1[4 * k + 1] * inv;
    float b2 = o1[4 * k + 2] * inv, b3 = o1[4 * k + 3] * inv;
    unsigned w0, w1, w2, w3;
    asm("v_cvt_pk_bf16_f32 %0, %1, %2" : "=v"(w0) : "v"(a0), "v"(a1));
    asm("v_cvt_pk_bf16_f32 %0, %1, %2" : "=v"(w1) : "v"(a2), "v"(a3));
    asm("v_cvt_pk_bf16_f32 %0, %1, %2" : "=v"(w2) : "v"(b0), "v"(b1));
    asm("v_cvt_pk_bf16_f32 %0, %1, %2" : "=v"(w3) : "v"(b2), "v"(b3));
    int d = 8 * k + 4 * hi;
    uint2 pa; pa.x = w0; pa.y = w1;
    uint2 pb; pb.x = w2; pb.y = w3;
    *(uint2*)&Os[l31 * 80 + d] = pa;
    *(uint2*)&Os[l31 * 80 + 32 + d] = pb;
  }
  __syncthreads();
  int b = bh >> 4, h = bh & 15;
#pragma unroll
  for (int pass = 0; pass < 4; pass++) {
    int qr = pass * 8 + (lane >> 3);
    int cc = lane & 7;
    bf16x8 v = *(const bf16x8*)&Os[qr * 80 + cc * 8];
    *(bf16x8*)&Ob[((size_t)(b * TT + q0 + w * 32 + qr)) * CDIM + h * 64 + cc * 8] = v;
  }
}

// ---------------- output projection GEMM ----------------
__global__ __launch_bounds__(256) void gemm_out(const short* __restrict__ A,
                                                const short* __restrict__ Bw,
                                                float* __restrict__ C) {
  const int K = CDIM;
  __shared__ __attribute__((aligned(16))) short As[128 * 32];
  __shared__ __attribute__((aligned(16))) short Bs[128 * 32];
  int tid = threadIdx.x;
  int bid = blockIdx.x;
  int bm = ((bid & 7) << 3) | (bid >> 3);   // T1: bijective on [0,64)
  int bn = blockIdx.y;
  int lane = tid & 63, wid = tid >> 6;
  int wr = wid >> 1, wc = wid & 1;
  int la = lane & 15, lg = lane >> 4;

  const short* Ab = A + (size_t)bm * 128 * K;
  const short* Bb = Bw + (size_t)bn * 128 * K;

  f32x4 acc[4][4];
#pragma unroll
  for (int m = 0; m < 4; m++)
#pragma unroll
    for (int n = 0; n < 4; n++) acc[m][n] = (f32x4){0.f, 0.f, 0.f, 0.f};

  int c0 = tid, c1 = tid + 256;
  for (int k0 = 0; k0 < K; k0 += 32) {
    GLOAD_LDS16(Ab + (c0 >> 2) * K + k0 + (c0 & 3) * 8, &As[c0 * 8]);
    GLOAD_LDS16(Ab + (c1 >> 2) * K + k0 + (c1 & 3) * 8, &As[c1 * 8]);
    GLOAD_LDS16(Bb + (c0 >> 2) * K + k0 + (c0 & 3) * 8, &Bs[c0 * 8]);
    GLOAD_LDS16(Bb + (c1 >> 2) * K + k0 + (c1 & 3) * 8, &Bs[c1 * 8]);
    __syncthreads();
    bf16x8 af[4], bfr[4];
#pragma unroll
    for (int m = 0; m < 4; m++)
      af[m] = *(const bf16x8*)&As[(wr * 64 + m * 16 + la) * 32 + lg * 8];
#pragma unroll
    for (int n = 0; n < 4; n++)
      bfr[n] = *(const bf16x8*)&Bs[(wc * 64 + n * 16 + la) * 32 + lg * 8];
#pragma unroll
    for (int m = 0; m < 4; m++)
#pragma unroll
      for (int n = 0; n < 4; n++)
        acc[m][n] = __builtin_amdgcn_mfma_f32_16x16x32_bf16(af[m], bfr[n],
                                                            acc[m][n], 0, 0, 0);
    __syncthreads();
  }

#pragma unroll
  for (int m = 0; m < 4; m++) {
    int rbase = bm * 128 + wr * 64 + m * 16 + lg * 4;
#pragma unroll
    for (int n = 0; n < 4; n++) {
      int col = bn * 128 + wc * 64 + n * 16 + la;
#pragma unroll
      for (int r = 0; r < 4; r++)
        C[(size_t)(rbase + r) * CDIM + col] = acc[m][n][r];
    }
  }
}

extern "C" void kernel_launch(void* const* d_in, const int* in_sizes, int n_in,
                              void* d_out, int out_size, void* d_ws, size_t ws_size,
                              hipStream_t stream) {
  const float* x    = (const float*)d_in[0];
  const float* wqkv = (const float*)d_in[1];
  const float* wo   = (const float*)d_in[2];
  float* out = (float*)d_out;

  char* ws = (char*)d_ws;
  short* xb  = (short*)(ws);
  short* wqb = (short*)(ws + (size_t)(16 << 20));
  short* wob = (short*)(ws + (size_t)(22 << 20));
  short* Qb  = (short*)(ws + (size_t)(24 << 20));
  short* Kb  = (short*)(ws + (size_t)(40 << 20));
  short* Vb  = (short*)(ws + (size_t)(56 << 20));   // V^T layout [B,H,Dh,T]
  short* Ob  = (short*)(ws + (size_t)(72 << 20));

  conv_bf16<<<8192, 256, 0, stream>>>(x, xb, BTROWS * CDIM);
  conv_bf16<<<3072, 256, 0, stream>>>(wqkv, wqb, NQKV * CDIM);
  conv_bf16<<<1024, 256, 0, stream>>>(wo, wob, CDIM * CDIM);

  gemm_qkv<<<dim3(BTROWS / 128, NQKV / 128), 256, 0, stream>>>(xb, wqb, Qb, Kb, Vb);
  attn_fwd2<<<NBATCH * 16 * (TT / 128), 256, 0, stream>>>(Qb, Kb, Vb, Ob);
  gemm_out<<<dim3(BTROWS / 128, CDIM / 128), 256, 0, stream>>>(Ob, wob, out);
}